// Round 18
// baseline (87.405 us; speedup 1.0000x reference)
//
#include <hip/hip_runtime.h>

#define BB 128
#define DD 8732
#define OO 16
#define CC 21
#define NBLK_C 35    // ceil(DD/256) blocks per image
#define NLB (BB * NBLK_C)
#define NV 35        // per-thread register values in topk

typedef __attribute__((address_space(3))) unsigned int lds_u32;
typedef const __attribute__((address_space(1))) unsigned int glb_u32;

__device__ __forceinline__ float smoothl1(float d) {
    float ad = fabsf(d);
    return (ad < 1.0f) ? 0.5f * d * d : ad - 0.5f;
}

// ---- kernel1: staged CE + inline match (atomicMax argmax) + SL1 -----------
// order: gt->LDS | barrier | issue async cls staging | IoU match (overlapped)
//        | barrier (drain) | atomicMax | CE from LDS
__global__ __launch_bounds__(256) void fused_all(
    const float4* __restrict__ loc_pred,   // [B*D]
    const float*  __restrict__ cls,        // [B*D*C]
    const float4* __restrict__ gt_boxes,   // [B*O]
    const int*    __restrict__ gt_labels,  // [B*O]
    const float4* __restrict__ db,         // [D]
    unsigned long long* __restrict__ partial, // [B*O] atomicMax targets, pre-zeroed
    float* __restrict__ ce_neg,            // [B*D]
    float* __restrict__ part_sl1,          // [NLB] layout [b][jb]
    int*   __restrict__ part_np,
    float* __restrict__ part_ce)
{
    const int b = blockIdx.y, jb = blockIdx.x, tid = threadIdx.x;
    const int d = jb * 256 + tid;
    __shared__ float s_cls[256 * CC];      // 21504 B
    __shared__ float s_ax1[OO], s_ay1[OO], s_ax2[OO], s_ay2[OO], s_area[OO];
    __shared__ int   s_lab[OO];
    __shared__ unsigned long long swave[4][OO];   // 512 B
    __shared__ float s_f[8];
    __shared__ int   s_i[4];

    // gt boxes to LDS first; barrier while nothing is in flight
    if (tid < OO) {
        float4 gg = gt_boxes[b * OO + tid];
        s_ax1[tid] = gg.x; s_ay1[tid] = gg.y; s_ax2[tid] = gg.z; s_ay2[tid] = gg.w;
        s_area[tid] = (gg.z - gg.x) * (gg.w - gg.y);
        s_lab[tid] = gt_labels[b * OO + tid];
    }
    __syncthreads();

    // issue async cls staging (16B/lane, linear LDS dest)
    const int nrow = min(256, DD - jb * 256);
    const int nvec = nrow * CC / 4;        // 1344 full, 147 tail
    const float4* src = (const float4*)(cls + ((size_t)b * DD + (size_t)jb * 256) * CC);
    if (nvec == 1344) {
        #pragma unroll
        for (int c = 0; c < 5; ++c) {
            int v = c * 256 + tid;
            __builtin_amdgcn_global_load_lds((glb_u32*)(src + v),
                                             (lds_u32*)&s_cls[v * 4], 16, 0, 0);
        }
        if (tid < 64) {
            int v = 5 * 256 + tid;
            __builtin_amdgcn_global_load_lds((glb_u32*)(src + v),
                                             (lds_u32*)&s_cls[v * 4], 16, 0, 0);
        }
    } else {
        for (int v = tid; v < nvec; v += 256)
            __builtin_amdgcn_global_load_lds((glb_u32*)(src + v),
                                             (lds_u32*)&s_cls[v * 4], 16, 0, 0);
    }

    // IoU matching for this thread's row (overlaps staging latency)
    unsigned long long key[OO];
    #pragma unroll
    for (int o = 0; o < OO; ++o) key[o] = 0ull;
    int lab = 0, bi = 0;
    if (d < DD) {
        float4 p = db[d];
        float px1 = p.x - p.z * 0.5f, py1 = p.y - p.w * 0.5f;
        float px2 = p.x + p.z * 0.5f, py2 = p.y + p.w * 0.5f;
        float area_b = (px2 - px1) * (py2 - py1);
        unsigned dl = (unsigned)(DD - 1 - d);
        float best = -1.0f;
        #pragma unroll
        for (int o = 0; o < OO; ++o) {
            float w = fmaxf(fminf(s_ax2[o], px2) - fmaxf(s_ax1[o], px1), 0.0f);
            float h = fmaxf(fminf(s_ay2[o], py2) - fmaxf(s_ay1[o], py1), 0.0f);
            float inter = w * h;
            float uni = s_area[o] + area_b - inter;
            float iou = inter * __builtin_amdgcn_rcpf(uni);   // v_rcp_f32
            unsigned long long kk = ((unsigned long long)__float_as_uint(iou) << 32) | dl;
            if (kk > key[o]) key[o] = kk;
            if (iou > best) { best = iou; bi = o; }   // first occurrence over o
        }
        lab = (best < 0.5f) ? 0 : s_lab[bi];
    }

    // per-wave u64 butterfly reduce of key[16] -> swave (no barrier yet)
    #pragma unroll
    for (int o = 0; o < OO; ++o) {
        unsigned long long k = key[o];
        #pragma unroll
        for (int off = 32; off; off >>= 1) {
            unsigned long long v = __shfl_xor(k, off);
            if (v > k) k = v;
        }
        if ((tid & 63) == 0) swave[tid >> 6][o] = k;
    }

    __syncthreads();   // drains staging (vmcnt) + swave LDS writes

    if (tid < OO) {
        unsigned long long m = swave[0][tid];
        #pragma unroll
        for (int w = 1; w < 4; ++w) if (swave[w][tid] > m) m = swave[w][tid];
        atomicMax(&partial[b * OO + tid], m);
    }

    // CE from LDS (word stride 21, coprime 32 -> 2-way = free)
    float sl1 = 0.0f, cepos = 0.0f; int npos = 0;
    if (d < DD) {
        const size_t gi = (size_t)b * DD + d;
        float m = s_cls[tid * CC];
        #pragma unroll
        for (int c = 1; c < CC; ++c) m = fmaxf(m, s_cls[tid * CC + c]);
        float s = 0.0f;
        #pragma unroll
        for (int c = 0; c < CC; ++c) s += __expf(s_cls[tid * CC + c] - m);
        float xl = s_cls[tid * CC + lab];
        float ce = m + __logf(s) - xl;

        if (lab > 0) {
            npos = 1; cepos = ce;
            float ax1 = s_ax1[bi], ay1 = s_ay1[bi], ax2 = s_ax2[bi], ay2 = s_ay2[bi];
            float cx = (ax1 + ax2) * 0.5f, cy = (ay1 + ay2) * 0.5f;
            float w = ax2 - ax1, h = ay2 - ay1;
            float4 p = db[d];
            float gx = (cx - p.x) / (p.z / 10.0f);
            float gy = (cy - p.y) / (p.w / 10.0f);
            float gw = __logf(w / p.z) * 5.0f;
            float gh = __logf(h / p.w) * 5.0f;
            float4 lp = loc_pred[gi];
            sl1 = smoothl1(lp.x - gx) + smoothl1(lp.y - gy)
                + smoothl1(lp.z - gw) + smoothl1(lp.w - gh);
        }
        ce_neg[gi] = (lab > 0) ? 0.0f : ce;
    }

    #pragma unroll
    for (int off = 32; off; off >>= 1) {
        sl1   += __shfl_xor(sl1, off);
        cepos += __shfl_xor(cepos, off);
        npos  += __shfl_xor(npos, off);
    }
    const int w = tid >> 6;
    if ((tid & 63) == 0) { s_f[w*2+0] = sl1; s_f[w*2+1] = cepos; s_i[w] = npos; }
    __syncthreads();
    if (tid == 0) {
        float sv = 0, cp = 0; int np = 0;
        #pragma unroll
        for (int q = 0; q < 4; ++q) { sv += s_f[q*2+0]; cp += s_f[q*2+1]; np += s_i[q]; }
        const int pi = b * NBLK_C + jb;
        part_sl1[pi] = sv;
        part_ce[pi]  = cp;
        part_np[pi]  = np;
    }
}

// ---- kernel2: per-image override fixup + radix topk + ticket finalize -----
__global__ __launch_bounds__(256) void topk_final(
    const float*  __restrict__ cls,
    const float4* __restrict__ loc_pred,
    const float4* __restrict__ gt_boxes,
    const int*    __restrict__ gt_labels,
    const float4* __restrict__ db,
    const unsigned long long* __restrict__ partial, // [B*O]
    float* __restrict__ ce_neg,               // patched in place
    const float* __restrict__ part_sl1,       // [NLB]
    const int*   __restrict__ part_np,
    const float* __restrict__ part_ce,
    float* __restrict__ img_sl1,              // [BB]
    float* __restrict__ img_ce,
    int*   __restrict__ img_np,
    float* __restrict__ conf_neg_part,
    int*   __restrict__ done_counter,
    float* __restrict__ out)
{
    const int b = blockIdx.x, tid = threadIdx.x;
    __shared__ int      hist[256];
    __shared__ unsigned s_pk[2];
    __shared__ float    s_f[12];
    __shared__ int      s_c[4];
    __shared__ int      s_bdi[OO], s_lab[OO];
    __shared__ float    s_ax1[OO], s_ay1[OO], s_ax2[OO], s_ay2[OO], s_area[OO];
    __shared__ float    s_dsl1, s_dce;
    __shared__ int      s_dnp, s_np;
    __shared__ float    s_isl1, s_ice;
    __shared__ int      s_last;

    if (tid < OO) {
        float4 gg = gt_boxes[b * OO + tid];
        s_ax1[tid] = gg.x; s_ay1[tid] = gg.y; s_ax2[tid] = gg.z; s_ay2[tid] = gg.w;
        s_area[tid] = (gg.z - gg.x) * (gg.w - gg.y);
        s_lab[tid] = gt_labels[b * OO + tid];
        s_bdi[tid] = DD - 1 - (int)(partial[b * OO + tid] & 0xffffffffu);
    }
    __syncthreads();

    // fixup: lanes 0..15; last-o-wins per row (winner = no larger o same row)
    float dsl1 = 0.0f, dce = 0.0f; int dnp = 0;
    if (tid < OO) {
        const int R = s_bdi[tid];
        bool winner = true;
        for (int o2 = tid + 1; o2 < OO; ++o2)
            if (s_bdi[o2] == R) winner = false;
        if (winner) {
            // recompute kernel1's lab0 for row R (identical formula)
            float4 p = db[R];
            float px1 = p.x - p.z * 0.5f, py1 = p.y - p.w * 0.5f;
            float px2 = p.x + p.z * 0.5f, py2 = p.y + p.w * 0.5f;
            float area_b = (px2 - px1) * (py2 - py1);
            float best = -1.0f; int bi = 0;
            #pragma unroll
            for (int o = 0; o < OO; ++o) {
                float w = fmaxf(fminf(s_ax2[o], px2) - fmaxf(s_ax1[o], px1), 0.0f);
                float h = fmaxf(fminf(s_ay2[o], py2) - fmaxf(s_ay1[o], py1), 0.0f);
                float inter = w * h;
                float uni = s_area[o] + area_b - inter;
                float iou = inter * __builtin_amdgcn_rcpf(uni);
                if (iou > best) { best = iou; bi = o; }
            }
            int lab0 = (best < 0.5f) ? 0 : s_lab[bi];

            const float* x = cls + ((size_t)b * DD + R) * CC;
            float m = x[0];
            #pragma unroll
            for (int c = 1; c < CC; ++c) m = fmaxf(m, x[c]);
            float s = 0.0f;
            #pragma unroll
            for (int c = 0; c < CC; ++c) s += __expf(x[c] - m);
            float lse = m + __logf(s);
            float4 lp = loc_pred[(size_t)b * DD + R];

            if (lab0 > 0) {      // remove old positive contribution
                dce -= (lse - x[lab0]);
                dnp -= 1;
                float ax1 = s_ax1[bi], ay1 = s_ay1[bi], ax2 = s_ax2[bi], ay2 = s_ay2[bi];
                float cx = (ax1 + ax2) * 0.5f, cy = (ay1 + ay2) * 0.5f;
                float w = ax2 - ax1, h = ay2 - ay1;
                float gx = (cx - p.x) / (p.z / 10.0f);
                float gy = (cy - p.y) / (p.w / 10.0f);
                float gw = __logf(w / p.z) * 5.0f;
                float gh = __logf(h / p.w) * 5.0f;
                dsl1 -= smoothl1(lp.x - gx) + smoothl1(lp.y - gy)
                      + smoothl1(lp.z - gw) + smoothl1(lp.w - gh);
            } else {
                ce_neg[(size_t)b * DD + R] = 0.0f;   // row becomes positive
            }
            // add new contribution (box = tid, label = s_lab[tid] > 0)
            dce += (lse - x[s_lab[tid]]);
            dnp += 1;
            {
                float ax1 = s_ax1[tid], ay1 = s_ay1[tid], ax2 = s_ax2[tid], ay2 = s_ay2[tid];
                float cx = (ax1 + ax2) * 0.5f, cy = (ay1 + ay2) * 0.5f;
                float w = ax2 - ax1, h = ay2 - ay1;
                float gx = (cx - p.x) / (p.z / 10.0f);
                float gy = (cy - p.y) / (p.w / 10.0f);
                float gw = __logf(w / p.z) * 5.0f;
                float gh = __logf(h / p.w) * 5.0f;
                dsl1 += smoothl1(lp.x - gx) + smoothl1(lp.y - gy)
                      + smoothl1(lp.z - gw) + smoothl1(lp.w - gh);
            }
        }
    }
    if (tid < 64) {       // 16-lane butterfly (lanes 16-63 carry zeros)
        #pragma unroll
        for (int off = 8; off; off >>= 1) {
            dsl1 += __shfl_xor(dsl1, off, 16);
            dce  += __shfl_xor(dce, off, 16);
            dnp  += __shfl_xor(dnp, off, 16);
        }
        if (tid == 0) { s_dsl1 = dsl1; s_dce = dce; s_dnp = dnp; }
    }
    __syncthreads();      // drains ce_neg patch stores + LDS

    if (tid == 0) {
        float a = 0, c2 = 0; int n = 0;
        #pragma unroll
        for (int j = 0; j < NBLK_C; ++j) {
            a  += part_sl1[b * NBLK_C + j];
            c2 += part_ce[b * NBLK_C + j];
            n  += part_np[b * NBLK_C + j];
        }
        s_isl1 = a + s_dsl1; s_ice = c2 + s_dce; s_np = n + s_dnp;
    }
    __syncthreads();

    int k0 = 3 * s_np;
    if (k0 > DD) k0 = DD;

    float row = 0.0f;
    if (k0 > 0) {
        unsigned kx[NV];
        #pragma unroll
        for (int q = 0; q < NV; ++q) {
            int d = q * 256 + tid;
            float v = (d < DD) ? ce_neg[(size_t)b * DD + d] : 0.0f;
            unsigned u = __float_as_uint(v);
            kx[q] = u ^ ((unsigned)((int)u >> 31) | 0x80000000u);
        }
        unsigned prefix = 0u; int k = k0;
        #pragma unroll
        for (int p = 0; p < 4; ++p) {
            const int shift = 24 - 8 * p;
            hist[tid] = 0;
            __syncthreads();
            #pragma unroll
            for (int q = 0; q < NV; ++q) {
                if (p == 0 || ((kx[q] ^ prefix) >> (shift + 8)) == 0u)
                    atomicAdd(&hist[(kx[q] >> shift) & 255], 1);
            }
            __syncthreads();
            if (tid < 64) {
                int h0 = hist[255 - 4*tid], h1 = hist[254 - 4*tid],
                    h2 = hist[253 - 4*tid], h3 = hist[252 - 4*tid];
                int sl = h0 + h1 + h2 + h3;
                int run = sl;
                #pragma unroll
                for (int off = 1; off < 64; off <<= 1) {
                    int v = __shfl_up(run, off);
                    if (tid >= off) run += v;
                }
                int pre = run - sl;
                if (pre < k && k <= pre + sl) {
                    int hh[4] = {h0, h1, h2, h3};
                    int c = pre, byte = -1, knew = 0;
                    #pragma unroll
                    for (int j = 0; j < 4; ++j) {
                        if (byte < 0 && c + hh[j] >= k) { byte = 255 - 4*tid - j; knew = k - c; }
                        c += hh[j];
                    }
                    s_pk[0] = prefix | ((unsigned)byte << shift);
                    s_pk[1] = (unsigned)knew;
                }
            }
            __syncthreads();
            prefix = s_pk[0]; k = (int)s_pk[1];
        }
        unsigned vb = (prefix & 0x80000000u) ? (prefix ^ 0x80000000u) : ~prefix;
        float vk = __uint_as_float(vb);

        float ssum = 0.0f; int cgt = 0;
        #pragma unroll
        for (int q = 0; q < NV; ++q) {
            if (kx[q] > prefix) {
                unsigned u = (kx[q] & 0x80000000u) ? (kx[q] ^ 0x80000000u) : ~kx[q];
                ssum += __uint_as_float(u);
                ++cgt;
            }
        }
        #pragma unroll
        for (int off = 32; off; off >>= 1) { ssum += __shfl_xor(ssum, off); cgt += __shfl_xor(cgt, off); }
        if ((tid & 63) == 0) { s_f[tid >> 6] = ssum; s_c[tid >> 6] = cgt; }
        __syncthreads();
        row = s_f[0]+s_f[1]+s_f[2]+s_f[3]
            + (float)(k0 - (s_c[0]+s_c[1]+s_c[2]+s_c[3])) * vk;
    }

    if (tid == 0) {
        conf_neg_part[b] = row;
        img_sl1[b] = s_isl1; img_ce[b] = s_ice; img_np[b] = s_np;
        __threadfence();
        int prev = atomicAdd(done_counter, 1);
        s_last = (prev == BB - 1) ? 1 : 0;
    }
    __syncthreads();
    if (s_last) {
        __threadfence();
        float loc = 0.0f, cp = 0.0f, cn = 0.0f; int npt = 0;
        if (tid < BB) {
            loc = img_sl1[tid]; cp = img_ce[tid];
            cn = conf_neg_part[tid]; npt = img_np[tid];
        }
        #pragma unroll
        for (int off = 32; off; off >>= 1) {
            loc += __shfl_xor(loc, off);
            cp  += __shfl_xor(cp, off);
            cn  += __shfl_xor(cn, off);
            npt += __shfl_xor(npt, off);
        }
        const int w = tid >> 6;
        if ((tid & 63) == 0) { s_f[w*3+0] = loc; s_f[w*3+1] = cp; s_f[w*3+2] = cn; s_c[w] = npt; }
        __syncthreads();
        if (tid == 0) {
            float L = 0, P = 0, N = 0; int T = 0;
            #pragma unroll
            for (int q = 0; q < 4; ++q) { L += s_f[q*3]; P += s_f[q*3+1]; N += s_f[q*3+2]; T += s_c[q]; }
            float npf = (float)T;
            out[0] = L / (npf * 4.0f) + (N + P) / npf;
        }
    }
}

extern "C" void kernel_launch(void* const* d_in, const int* in_sizes, int n_in,
                              void* d_out, int out_size, void* d_ws, size_t ws_size,
                              hipStream_t stream) {
    (void)in_sizes; (void)n_in; (void)out_size; (void)ws_size;
    const float4* loc_pred  = (const float4*)d_in[0];
    const float*  cls_pred  = (const float*)d_in[1];
    const float4* gt_boxes  = (const float4*)d_in[2];
    const int*    gt_labels = (const int*)d_in[3];
    const float4* db        = (const float4*)d_in[4];

    char* ws = (char*)d_ws;
    size_t off = 0;
    auto alloc = [&](size_t bytes) { char* p = ws + off; off = (off + bytes + 15) & ~(size_t)15; return p; };

    unsigned long long* partial = (unsigned long long*)alloc((size_t)BB * OO * 8);
    int*   done_counter  = (int*)alloc(16);      // adjacent to partial -> one memset
    float* ce_neg        = (float*)alloc((size_t)BB * DD * 4);
    float* part_sl1      = (float*)alloc((size_t)NLB * 4);
    int*   part_np       = (int*)alloc((size_t)NLB * 4);
    float* part_ce       = (float*)alloc((size_t)NLB * 4);
    float* img_sl1       = (float*)alloc((size_t)BB * 4);
    float* img_ce        = (float*)alloc((size_t)BB * 4);
    int*   img_np        = (int*)alloc((size_t)BB * 4);
    float* conf_neg_part = (float*)alloc((size_t)BB * 4);

    // zero argmax targets + ticket counter (16 KB + 16 B, contiguous)
    hipMemsetAsync(partial, 0, (size_t)BB * OO * 8 + 16, stream);

    fused_all<<<dim3(NBLK_C, BB), 256, 0, stream>>>(loc_pred, cls_pred, gt_boxes,
                                                    gt_labels, db, partial,
                                                    ce_neg, part_sl1, part_np, part_ce);
    topk_final<<<BB, 256, 0, stream>>>(cls_pred, loc_pred, gt_boxes, gt_labels, db,
                                       partial, ce_neg, part_sl1, part_np, part_ce,
                                       img_sl1, img_ce, img_np, conf_neg_part,
                                       done_counter, (float*)d_out);
}

// Round 19
// 67.093 us; speedup vs baseline: 1.3028x; 1.3028x over previous
//
#include <hip/hip_runtime.h>

#define BB 128
#define DD 8732
#define OO 16
#define CC 21
#define NG2 4366     // DD/2 groups of 2 rows
#define NBLK_C 18    // ceil(NG2/256)
#define NLB (BB * NBLK_C)
#define NV 35        // per-thread register values in topk

typedef float f32x2 __attribute__((ext_vector_type(2)));

__device__ __forceinline__ float smoothl1(float d) {
    float ad = fabsf(d);
    return (ad < 1.0f) ? 0.5f * d * d : ad - 0.5f;
}

// ---- kernel1: streaming match + CE + SL1; u32 packed argmax keys ----------
// key = (iou_bits & ~0x3FFF) | (16383 - d): 18-bit iou, tie -> smallest d
__global__ __launch_bounds__(256) void fused_all(
    const float4* __restrict__ loc_pred,   // [B*D]
    const float*  __restrict__ cls,        // [B*D*C]
    const float4* __restrict__ gt_boxes,   // [B*O]
    const int*    __restrict__ gt_labels,  // [B*O]
    const float4* __restrict__ db,         // [D]
    unsigned* __restrict__ partial,        // [B*O] atomicMax targets, pre-zeroed
    float* __restrict__ ce_neg,            // [B*D]
    float* __restrict__ part_sl1,          // [NLB] layout [b][jb]
    int*   __restrict__ part_np,
    float* __restrict__ part_ce)
{
    const int b = blockIdx.y, jb = blockIdx.x, tid = threadIdx.x;
    const int g = jb * 256 + tid;          // 2-row group id
    __shared__ float s_ax1[OO], s_ay1[OO], s_ax2[OO], s_ay2[OO], s_area[OO];
    __shared__ int   s_lab[OO];
    __shared__ unsigned swave[4][OO];      // 256 B
    __shared__ float s_f[8];
    __shared__ int   s_i[4];

    if (tid < OO) {
        float4 gg = gt_boxes[b * OO + tid];
        s_ax1[tid] = gg.x; s_ay1[tid] = gg.y; s_ax2[tid] = gg.z; s_ay2[tid] = gg.w;
        s_area[tid] = (gg.z - gg.x) * (gg.w - gg.y);
        s_lab[tid] = gt_labels[b * OO + tid];
    }
    __syncthreads();

    const int row0 = g * 2;
    const size_t gi2 = (size_t)b * DD + row0;

    // issue cls loads FIRST: 21 independent float2 loads stay in flight
    // under the IoU match compute below
    float e[42];
    if (g < NG2) {
        const f32x2* src = (const f32x2*)(cls + gi2 * CC);
        #pragma unroll
        for (int jv = 0; jv < 21; ++jv) {
            f32x2 q = src[jv];
            e[2*jv+0] = q[0]; e[2*jv+1] = q[1];
        }
    }

    // IoU match: exact f32 per-row best; u32 packed per-o keys
    unsigned key[OO];
    #pragma unroll
    for (int o = 0; o < OO; ++o) key[o] = 0u;
    int lab_r[2] = {0, 0};
    int bi_r[2]  = {0, 0};

    if (g < NG2) {
        #pragma unroll
        for (int r = 0; r < 2; ++r) {
            const int d = row0 + r;
            float4 p = db[d];
            float px1 = p.x - p.z * 0.5f, py1 = p.y - p.w * 0.5f;
            float px2 = p.x + p.z * 0.5f, py2 = p.y + p.w * 0.5f;
            float area_b = (px2 - px1) * (py2 - py1);
            const unsigned dl = (unsigned)(16383 - d);
            float best = -1.0f; int bi = 0;
            #pragma unroll
            for (int o = 0; o < OO; ++o) {
                float w = fmaxf(fminf(s_ax2[o], px2) - fmaxf(s_ax1[o], px1), 0.0f);
                float h = fmaxf(fminf(s_ay2[o], py2) - fmaxf(s_ay1[o], py1), 0.0f);
                float inter = w * h;
                float uni = s_area[o] + area_b - inter;
                float iou = inter * __builtin_amdgcn_rcpf(uni);
                unsigned kk = (__float_as_uint(iou) & 0xFFFFC000u) | dl;
                if (kk > key[o]) key[o] = kk;
                if (iou > best) { best = iou; bi = o; }   // first occurrence over o
            }
            lab_r[r] = (best < 0.5f) ? 0 : s_lab[bi];
            bi_r[r]  = bi;
        }
    }

    // per-wave u32 butterfly reduce -> swave -> 16 atomicMax per block
    #pragma unroll
    for (int o = 0; o < OO; ++o) {
        unsigned k = key[o];
        #pragma unroll
        for (int off = 32; off; off >>= 1) {
            unsigned v = __shfl_xor(k, off);
            if (v > k) k = v;
        }
        if ((tid & 63) == 0) swave[tid >> 6][o] = k;
    }
    __syncthreads();
    if (tid < OO) {
        unsigned m = swave[0][tid];
        #pragma unroll
        for (int w = 1; w < 4; ++w) if (swave[w][tid] > m) m = swave[w][tid];
        atomicMax(&partial[b * OO + tid], m);
    }

    // CE phase (consumes e[], loaded long ago)
    float sl1 = 0.0f, cepos = 0.0f; int npos = 0;
    if (g < NG2) {
        float out[2];
        #pragma unroll
        for (int r = 0; r < 2; ++r) {
            const int lab = lab_r[r];
            float m = e[21*r];
            #pragma unroll
            for (int c = 1; c < CC; ++c) m = fmaxf(m, e[21*r + c]);
            float s = 0.0f;
            #pragma unroll
            for (int c = 0; c < CC; ++c) s += __expf(e[21*r + c] - m);
            float xl = (lab == 0) ? e[21*r] : cls[(gi2 + r) * CC + lab];
            float ce = m + __logf(s) - xl;
            if (lab > 0) {
                npos += 1; cepos += ce;
                const int bi = bi_r[r];
                float ax1 = s_ax1[bi], ay1 = s_ay1[bi], ax2 = s_ax2[bi], ay2 = s_ay2[bi];
                float cx = (ax1 + ax2) * 0.5f, cy = (ay1 + ay2) * 0.5f;
                float w = ax2 - ax1, h = ay2 - ay1;
                float4 p = db[row0 + r];
                float gx = (cx - p.x) / (p.z / 10.0f);
                float gy = (cy - p.y) / (p.w / 10.0f);
                float gw = __logf(w / p.z) * 5.0f;
                float gh = __logf(h / p.w) * 5.0f;
                float4 lp = loc_pred[gi2 + r];
                sl1 += smoothl1(lp.x - gx) + smoothl1(lp.y - gy)
                     + smoothl1(lp.z - gw) + smoothl1(lp.w - gh);
                out[r] = 0.0f;
            } else {
                out[r] = ce;
            }
        }
        *(f32x2*)(ce_neg + gi2) = f32x2{out[0], out[1]};
    }

    #pragma unroll
    for (int off = 32; off; off >>= 1) {
        sl1   += __shfl_xor(sl1, off);
        cepos += __shfl_xor(cepos, off);
        npos  += __shfl_xor(npos, off);
    }
    const int w = tid >> 6;
    if ((tid & 63) == 0) { s_f[w*2+0] = sl1; s_f[w*2+1] = cepos; s_i[w] = npos; }
    __syncthreads();
    if (tid == 0) {
        float sv = 0, cp = 0; int np = 0;
        #pragma unroll
        for (int q = 0; q < 4; ++q) { sv += s_f[q*2+0]; cp += s_f[q*2+1]; np += s_i[q]; }
        const int pi = b * NBLK_C + jb;
        part_sl1[pi] = sv;
        part_ce[pi]  = cp;
        part_np[pi]  = np;
    }
}

// ---- kernel2: per-image override fixup + radix topk + ticket finalize -----
__global__ __launch_bounds__(256) void topk_final(
    const float*  __restrict__ cls,
    const float4* __restrict__ loc_pred,
    const float4* __restrict__ gt_boxes,
    const int*    __restrict__ gt_labels,
    const float4* __restrict__ db,
    const unsigned* __restrict__ partial,     // [B*O]
    float* __restrict__ ce_neg,               // patched in place
    const float* __restrict__ part_sl1,       // [NLB]
    const int*   __restrict__ part_np,
    const float* __restrict__ part_ce,
    float* __restrict__ img_sl1,              // [BB]
    float* __restrict__ img_ce,
    int*   __restrict__ img_np,
    float* __restrict__ conf_neg_part,
    int*   __restrict__ done_counter,
    float* __restrict__ out)
{
    const int b = blockIdx.x, tid = threadIdx.x;
    __shared__ int      hist[256];
    __shared__ unsigned s_pk[2];
    __shared__ float    s_f[12];
    __shared__ int      s_c[4];
    __shared__ int      s_bdi[OO], s_lab[OO];
    __shared__ float    s_ax1[OO], s_ay1[OO], s_ax2[OO], s_ay2[OO], s_area[OO];
    __shared__ float    s_dsl1, s_dce;
    __shared__ int      s_dnp, s_np;
    __shared__ float    s_isl1, s_ice;
    __shared__ int      s_last;

    if (tid < OO) {
        float4 gg = gt_boxes[b * OO + tid];
        s_ax1[tid] = gg.x; s_ay1[tid] = gg.y; s_ax2[tid] = gg.z; s_ay2[tid] = gg.w;
        s_area[tid] = (gg.z - gg.x) * (gg.w - gg.y);
        s_lab[tid] = gt_labels[b * OO + tid];
        s_bdi[tid] = 16383 - (int)(partial[b * OO + tid] & 0x3FFFu);
    }
    __syncthreads();

    // fixup: lanes 0..15; last-o-wins per row (winner = no larger o same row)
    float dsl1 = 0.0f, dce = 0.0f; int dnp = 0;
    if (tid < OO) {
        const int R = s_bdi[tid];
        bool winner = true;
        for (int o2 = tid + 1; o2 < OO; ++o2)
            if (s_bdi[o2] == R) winner = false;
        if (winner) {
            // recompute kernel1's lab0 for row R (identical formula)
            float4 p = db[R];
            float px1 = p.x - p.z * 0.5f, py1 = p.y - p.w * 0.5f;
            float px2 = p.x + p.z * 0.5f, py2 = p.y + p.w * 0.5f;
            float area_b = (px2 - px1) * (py2 - py1);
            float best = -1.0f; int bi = 0;
            #pragma unroll
            for (int o = 0; o < OO; ++o) {
                float w = fmaxf(fminf(s_ax2[o], px2) - fmaxf(s_ax1[o], px1), 0.0f);
                float h = fmaxf(fminf(s_ay2[o], py2) - fmaxf(s_ay1[o], py1), 0.0f);
                float inter = w * h;
                float uni = s_area[o] + area_b - inter;
                float iou = inter * __builtin_amdgcn_rcpf(uni);
                if (iou > best) { best = iou; bi = o; }
            }
            int lab0 = (best < 0.5f) ? 0 : s_lab[bi];

            const float* x = cls + ((size_t)b * DD + R) * CC;
            float m = x[0];
            #pragma unroll
            for (int c = 1; c < CC; ++c) m = fmaxf(m, x[c]);
            float s = 0.0f;
            #pragma unroll
            for (int c = 0; c < CC; ++c) s += __expf(x[c] - m);
            float lse = m + __logf(s);
            float4 lp = loc_pred[(size_t)b * DD + R];

            if (lab0 > 0) {      // remove old positive contribution
                dce -= (lse - x[lab0]);
                dnp -= 1;
                float ax1 = s_ax1[bi], ay1 = s_ay1[bi], ax2 = s_ax2[bi], ay2 = s_ay2[bi];
                float cx = (ax1 + ax2) * 0.5f, cy = (ay1 + ay2) * 0.5f;
                float w = ax2 - ax1, h = ay2 - ay1;
                float gx = (cx - p.x) / (p.z / 10.0f);
                float gy = (cy - p.y) / (p.w / 10.0f);
                float gw = __logf(w / p.z) * 5.0f;
                float gh = __logf(h / p.w) * 5.0f;
                dsl1 -= smoothl1(lp.x - gx) + smoothl1(lp.y - gy)
                      + smoothl1(lp.z - gw) + smoothl1(lp.w - gh);
            } else {
                ce_neg[(size_t)b * DD + R] = 0.0f;   // row becomes positive
            }
            // add new contribution (box = tid, label = s_lab[tid] > 0)
            dce += (lse - x[s_lab[tid]]);
            dnp += 1;
            {
                float ax1 = s_ax1[tid], ay1 = s_ay1[tid], ax2 = s_ax2[tid], ay2 = s_ay2[tid];
                float cx = (ax1 + ax2) * 0.5f, cy = (ay1 + ay2) * 0.5f;
                float w = ax2 - ax1, h = ay2 - ay1;
                float gx = (cx - p.x) / (p.z / 10.0f);
                float gy = (cy - p.y) / (p.w / 10.0f);
                float gw = __logf(w / p.z) * 5.0f;
                float gh = __logf(h / p.w) * 5.0f;
                dsl1 += smoothl1(lp.x - gx) + smoothl1(lp.y - gy)
                      + smoothl1(lp.z - gw) + smoothl1(lp.w - gh);
            }
        }
    }
    if (tid < 64) {       // 16-lane butterfly (lanes 16-63 carry zeros)
        #pragma unroll
        for (int off = 8; off; off >>= 1) {
            dsl1 += __shfl_xor(dsl1, off, 16);
            dce  += __shfl_xor(dce, off, 16);
            dnp  += __shfl_xor(dnp, off, 16);
        }
        if (tid == 0) { s_dsl1 = dsl1; s_dce = dce; s_dnp = dnp; }
    }
    __syncthreads();      // drains ce_neg patch stores + LDS

    if (tid == 0) {
        float a = 0, c2 = 0; int n = 0;
        #pragma unroll
        for (int j = 0; j < NBLK_C; ++j) {
            a  += part_sl1[b * NBLK_C + j];
            c2 += part_ce[b * NBLK_C + j];
            n  += part_np[b * NBLK_C + j];
        }
        s_isl1 = a + s_dsl1; s_ice = c2 + s_dce; s_np = n + s_dnp;
    }
    __syncthreads();

    int k0 = 3 * s_np;
    if (k0 > DD) k0 = DD;

    float row = 0.0f;
    if (k0 > 0) {
        unsigned kx[NV];
        #pragma unroll
        for (int q = 0; q < NV; ++q) {
            int d = q * 256 + tid;
            float v = (d < DD) ? ce_neg[(size_t)b * DD + d] : 0.0f;
            unsigned u = __float_as_uint(v);
            kx[q] = u ^ ((unsigned)((int)u >> 31) | 0x80000000u);
        }
        unsigned prefix = 0u; int k = k0;
        #pragma unroll
        for (int p = 0; p < 4; ++p) {
            const int shift = 24 - 8 * p;
            hist[tid] = 0;
            __syncthreads();
            #pragma unroll
            for (int q = 0; q < NV; ++q) {
                if (p == 0 || ((kx[q] ^ prefix) >> (shift + 8)) == 0u)
                    atomicAdd(&hist[(kx[q] >> shift) & 255], 1);
            }
            __syncthreads();
            if (tid < 64) {
                int h0 = hist[255 - 4*tid], h1 = hist[254 - 4*tid],
                    h2 = hist[253 - 4*tid], h3 = hist[252 - 4*tid];
                int sl = h0 + h1 + h2 + h3;
                int run = sl;
                #pragma unroll
                for (int off = 1; off < 64; off <<= 1) {
                    int v = __shfl_up(run, off);
                    if (tid >= off) run += v;
                }
                int pre = run - sl;
                if (pre < k && k <= pre + sl) {
                    int hh[4] = {h0, h1, h2, h3};
                    int c = pre, byte = -1, knew = 0;
                    #pragma unroll
                    for (int j = 0; j < 4; ++j) {
                        if (byte < 0 && c + hh[j] >= k) { byte = 255 - 4*tid - j; knew = k - c; }
                        c += hh[j];
                    }
                    s_pk[0] = prefix | ((unsigned)byte << shift);
                    s_pk[1] = (unsigned)knew;
                }
            }
            __syncthreads();
            prefix = s_pk[0]; k = (int)s_pk[1];
        }
        unsigned vb = (prefix & 0x80000000u) ? (prefix ^ 0x80000000u) : ~prefix;
        float vk = __uint_as_float(vb);

        float ssum = 0.0f; int cgt = 0;
        #pragma unroll
        for (int q = 0; q < NV; ++q) {
            if (kx[q] > prefix) {
                unsigned u = (kx[q] & 0x80000000u) ? (kx[q] ^ 0x80000000u) : ~kx[q];
                ssum += __uint_as_float(u);
                ++cgt;
            }
        }
        #pragma unroll
        for (int off = 32; off; off >>= 1) { ssum += __shfl_xor(ssum, off); cgt += __shfl_xor(cgt, off); }
        if ((tid & 63) == 0) { s_f[tid >> 6] = ssum; s_c[tid >> 6] = cgt; }
        __syncthreads();
        row = s_f[0]+s_f[1]+s_f[2]+s_f[3]
            + (float)(k0 - (s_c[0]+s_c[1]+s_c[2]+s_c[3])) * vk;
    }

    if (tid == 0) {
        conf_neg_part[b] = row;
        img_sl1[b] = s_isl1; img_ce[b] = s_ice; img_np[b] = s_np;
        __threadfence();
        int prev = atomicAdd(done_counter, 1);
        s_last = (prev == BB - 1) ? 1 : 0;
    }
    __syncthreads();
    if (s_last) {
        __threadfence();
        float loc = 0.0f, cp = 0.0f, cn = 0.0f; int npt = 0;
        if (tid < BB) {
            loc = img_sl1[tid]; cp = img_ce[tid];
            cn = conf_neg_part[tid]; npt = img_np[tid];
        }
        #pragma unroll
        for (int off = 32; off; off >>= 1) {
            loc += __shfl_xor(loc, off);
            cp  += __shfl_xor(cp, off);
            cn  += __shfl_xor(cn, off);
            npt += __shfl_xor(npt, off);
        }
        const int w = tid >> 6;
        if ((tid & 63) == 0) { s_f[w*3+0] = loc; s_f[w*3+1] = cp; s_f[w*3+2] = cn; s_c[w] = npt; }
        __syncthreads();
        if (tid == 0) {
            float L = 0, P = 0, N = 0; int T = 0;
            #pragma unroll
            for (int q = 0; q < 4; ++q) { L += s_f[q*3]; P += s_f[q*3+1]; N += s_f[q*3+2]; T += s_c[q]; }
            float npf = (float)T;
            out[0] = L / (npf * 4.0f) + (N + P) / npf;
        }
    }
}

extern "C" void kernel_launch(void* const* d_in, const int* in_sizes, int n_in,
                              void* d_out, int out_size, void* d_ws, size_t ws_size,
                              hipStream_t stream) {
    (void)in_sizes; (void)n_in; (void)out_size; (void)ws_size;
    const float4* loc_pred  = (const float4*)d_in[0];
    const float*  cls_pred  = (const float*)d_in[1];
    const float4* gt_boxes  = (const float4*)d_in[2];
    const int*    gt_labels = (const int*)d_in[3];
    const float4* db        = (const float4*)d_in[4];

    char* ws = (char*)d_ws;
    size_t off = 0;
    auto alloc = [&](size_t bytes) { char* p = ws + off; off = (off + bytes + 15) & ~(size_t)15; return p; };

    unsigned* partial    = (unsigned*)alloc((size_t)BB * OO * 4);   // 8 KB
    int*   done_counter  = (int*)alloc(16);      // adjacent to partial -> one memset
    float* ce_neg        = (float*)alloc((size_t)BB * DD * 4);
    float* part_sl1      = (float*)alloc((size_t)NLB * 4);
    int*   part_np       = (int*)alloc((size_t)NLB * 4);
    float* part_ce       = (float*)alloc((size_t)NLB * 4);
    float* img_sl1       = (float*)alloc((size_t)BB * 4);
    float* img_ce        = (float*)alloc((size_t)BB * 4);
    int*   img_np        = (int*)alloc((size_t)BB * 4);
    float* conf_neg_part = (float*)alloc((size_t)BB * 4);

    // zero argmax targets + ticket counter (8 KB + 16 B, contiguous)
    hipMemsetAsync(partial, 0, (size_t)BB * OO * 4 + 16, stream);

    fused_all<<<dim3(NBLK_C, BB), 256, 0, stream>>>(loc_pred, cls_pred, gt_boxes,
                                                    gt_labels, db, partial,
                                                    ce_neg, part_sl1, part_np, part_ce);
    topk_final<<<BB, 256, 0, stream>>>(cls_pred, loc_pred, gt_boxes, gt_labels, db,
                                       partial, ce_neg, part_sl1, part_np, part_ce,
                                       img_sl1, img_ce, img_np, conf_neg_part,
                                       done_counter, (float*)d_out);
}

// Round 20
// 59.860 us; speedup vs baseline: 1.4602x; 1.1208x over previous
//
#include <hip/hip_runtime.h>

#define BB 128
#define DD 8732
#define OO 16
#define CC 21
#define NG2 4366     // DD/2 groups of 2 rows
#define NBLK_C 18    // ceil(NG2/256)
#define NLB (BB * NBLK_C)
#define NV 35        // per-thread register values in topk

typedef float f32x2 __attribute__((ext_vector_type(2)));

__device__ __forceinline__ float smoothl1(float d) {
    float ad = fabsf(d);
    return (ad < 1.0f) ? 0.5f * d * d : ad - 0.5f;
}

// ---- kernel1: streaming match + CE + SL1 (no override), atomicMax argmax --
// 2 rows/thread; grid (18,128)=2304 blocks = 9 blocks/CU (LDS-cap-matched)
__global__ __launch_bounds__(256) void fused_all(
    const float4* __restrict__ loc_pred,   // [B*D]
    const float*  __restrict__ cls,        // [B*D*C]
    const float4* __restrict__ gt_boxes,   // [B*O]
    const int*    __restrict__ gt_labels,  // [B*O]
    const float4* __restrict__ db,         // [D]
    unsigned long long* __restrict__ partial, // [B*O] atomicMax targets, pre-zeroed
    float* __restrict__ ce_neg,            // [B*D]
    float* __restrict__ part_sl1,          // [NLB] layout [b][jb]
    int*   __restrict__ part_np,
    float* __restrict__ part_ce)
{
    const int b = blockIdx.y, jb = blockIdx.x, tid = threadIdx.x;
    const int g = jb * 256 + tid;          // 2-row group id
    __shared__ float s_ax1[OO], s_ay1[OO], s_ax2[OO], s_ay2[OO], s_area[OO];
    __shared__ int   s_lab[OO];
    __shared__ unsigned long long s_keys[8][257];
    __shared__ float s_f[8];
    __shared__ int   s_i[4];

    if (tid < OO) {
        float4 gg = gt_boxes[b * OO + tid];
        s_ax1[tid] = gg.x; s_ay1[tid] = gg.y; s_ax2[tid] = gg.z; s_ay2[tid] = gg.w;
        s_area[tid] = (gg.z - gg.x) * (gg.w - gg.y);
        s_lab[tid] = gt_labels[b * OO + tid];
    }
    __syncthreads();

    unsigned long long key[OO];
    #pragma unroll
    for (int o = 0; o < OO; ++o) key[o] = 0ull;
    int lab_r[2] = {0, 0};
    int bi_r[2]  = {0, 0};

    const int row0 = g * 2;
    if (g < NG2) {
        #pragma unroll
        for (int r = 0; r < 2; ++r) {
            const int d = row0 + r;
            float4 p = db[d];
            float px1 = p.x - p.z * 0.5f, py1 = p.y - p.w * 0.5f;
            float px2 = p.x + p.z * 0.5f, py2 = p.y + p.w * 0.5f;
            float area_b = (px2 - px1) * (py2 - py1);
            unsigned dl = (unsigned)(DD - 1 - d);
            float best = -1.0f; int bi = 0;
            #pragma unroll
            for (int o = 0; o < OO; ++o) {
                float w = fmaxf(fminf(s_ax2[o], px2) - fmaxf(s_ax1[o], px1), 0.0f);
                float h = fmaxf(fminf(s_ay2[o], py2) - fmaxf(s_ay1[o], py1), 0.0f);
                float inter = w * h;
                float uni = s_area[o] + area_b - inter;
                float iou = inter * __builtin_amdgcn_rcpf(uni);
                unsigned long long kk = ((unsigned long long)__float_as_uint(iou) << 32) | dl;
                if (kk > key[o]) key[o] = kk;
                if (iou > best) { best = iou; bi = o; }   // first occurrence over o
            }
            lab_r[r] = (best < 0.5f) ? 0 : s_lab[bi];
            bi_r[r]  = bi;
        }
    }

    // block-reduce keys (two 8-o passes) -> 16 atomicMax per block
    #pragma unroll
    for (int o = 0; o < 8; ++o) s_keys[o][tid] = key[o];
    __syncthreads();
    if (tid < 128) {
        const int o = tid >> 4, j = tid & 15;
        unsigned long long mx = s_keys[o][j];
        #pragma unroll
        for (int m = 1; m < 16; ++m) {
            unsigned long long v = s_keys[o][j + 16 * m];
            if (v > mx) mx = v;
        }
        #pragma unroll
        for (int off = 8; off; off >>= 1) {
            unsigned long long v = __shfl_xor(mx, off, 16);
            if (v > mx) mx = v;
        }
        if (j == 0) atomicMax(&partial[b * OO + o], mx);
    }
    __syncthreads();
    #pragma unroll
    for (int o = 0; o < 8; ++o) s_keys[o][tid] = key[8 + o];
    __syncthreads();
    if (tid < 128) {
        const int o = tid >> 4, j = tid & 15;
        unsigned long long mx = s_keys[o][j];
        #pragma unroll
        for (int m = 1; m < 16; ++m) {
            unsigned long long v = s_keys[o][j + 16 * m];
            if (v > mx) mx = v;
        }
        #pragma unroll
        for (int off = 8; off; off >>= 1) {
            unsigned long long v = __shfl_xor(mx, off, 16);
            if (v > mx) mx = v;
        }
        if (j == 0) atomicMax(&partial[b * OO + 8 + o], mx);
    }

    // CE phase: 21 independent aligned float2 loads (168B/group, 8B-aligned)
    float sl1 = 0.0f, cepos = 0.0f; int npos = 0;
    if (g < NG2) {
        const size_t gi2 = (size_t)b * DD + row0;
        float e[42];
        const f32x2* src = (const f32x2*)(cls + gi2 * CC);
        #pragma unroll
        for (int jv = 0; jv < 21; ++jv) {
            f32x2 q = src[jv];
            e[2*jv+0] = q[0]; e[2*jv+1] = q[1];
        }
        float out[2];
        #pragma unroll
        for (int r = 0; r < 2; ++r) {
            const int lab = lab_r[r];
            float m = e[21*r];
            #pragma unroll
            for (int c = 1; c < CC; ++c) m = fmaxf(m, e[21*r + c]);
            float s = 0.0f;
            #pragma unroll
            for (int c = 0; c < CC; ++c) s += __expf(e[21*r + c] - m);
            float xl = (lab == 0) ? e[21*r] : cls[(gi2 + r) * CC + lab];
            float ce = m + __logf(s) - xl;
            if (lab > 0) {
                npos += 1; cepos += ce;
                const int bi = bi_r[r];
                float ax1 = s_ax1[bi], ay1 = s_ay1[bi], ax2 = s_ax2[bi], ay2 = s_ay2[bi];
                float cx = (ax1 + ax2) * 0.5f, cy = (ay1 + ay2) * 0.5f;
                float w = ax2 - ax1, h = ay2 - ay1;
                float4 p = db[row0 + r];
                float gx = (cx - p.x) / (p.z / 10.0f);
                float gy = (cy - p.y) / (p.w / 10.0f);
                float gw = __logf(w / p.z) * 5.0f;
                float gh = __logf(h / p.w) * 5.0f;
                float4 lp = loc_pred[gi2 + r];
                sl1 += smoothl1(lp.x - gx) + smoothl1(lp.y - gy)
                     + smoothl1(lp.z - gw) + smoothl1(lp.w - gh);
                out[r] = 0.0f;
            } else {
                out[r] = ce;
            }
        }
        *(f32x2*)(ce_neg + gi2) = f32x2{out[0], out[1]};
    }

    #pragma unroll
    for (int off = 32; off; off >>= 1) {
        sl1   += __shfl_xor(sl1, off);
        cepos += __shfl_xor(cepos, off);
        npos  += __shfl_xor(npos, off);
    }
    const int w = tid >> 6;
    if ((tid & 63) == 0) { s_f[w*2+0] = sl1; s_f[w*2+1] = cepos; s_i[w] = npos; }
    __syncthreads();
    if (tid == 0) {
        float sv = 0, cp = 0; int np = 0;
        #pragma unroll
        for (int q = 0; q < 4; ++q) { sv += s_f[q*2+0]; cp += s_f[q*2+1]; np += s_i[q]; }
        const int pi = b * NBLK_C + jb;
        part_sl1[pi] = sv;
        part_ce[pi]  = cp;
        part_np[pi]  = np;
    }
}

// ---- kernel2: per-image override fixup + radix topk + ticket finalize -----
__global__ __launch_bounds__(256) void topk_final(
    const float*  __restrict__ cls,
    const float4* __restrict__ loc_pred,
    const float4* __restrict__ gt_boxes,
    const int*    __restrict__ gt_labels,
    const float4* __restrict__ db,
    const unsigned long long* __restrict__ partial, // [B*O]
    float* __restrict__ ce_neg,               // patched in place
    const float* __restrict__ part_sl1,       // [NLB]
    const int*   __restrict__ part_np,
    const float* __restrict__ part_ce,
    float* __restrict__ img_sl1,              // [BB]
    float* __restrict__ img_ce,
    int*   __restrict__ img_np,
    float* __restrict__ conf_neg_part,
    int*   __restrict__ done_counter,
    float* __restrict__ out)
{
    const int b = blockIdx.x, tid = threadIdx.x;
    __shared__ int      hist[256];
    __shared__ unsigned s_pk[2];
    __shared__ float    s_f[12];
    __shared__ int      s_c[4];
    __shared__ int      s_bdi[OO], s_lab[OO];
    __shared__ float    s_ax1[OO], s_ay1[OO], s_ax2[OO], s_ay2[OO], s_area[OO];
    __shared__ float    s_dsl1, s_dce;
    __shared__ int      s_dnp, s_np;
    __shared__ float    s_isl1, s_ice;
    __shared__ int      s_last;

    if (tid < OO) {
        float4 gg = gt_boxes[b * OO + tid];
        s_ax1[tid] = gg.x; s_ay1[tid] = gg.y; s_ax2[tid] = gg.z; s_ay2[tid] = gg.w;
        s_area[tid] = (gg.z - gg.x) * (gg.w - gg.y);
        s_lab[tid] = gt_labels[b * OO + tid];
        s_bdi[tid] = DD - 1 - (int)(partial[b * OO + tid] & 0xffffffffu);
    }
    __syncthreads();

    // fixup: lanes 0..15; last-o-wins per row (winner = no larger o same row)
    float dsl1 = 0.0f, dce = 0.0f; int dnp = 0;
    if (tid < OO) {
        const int R = s_bdi[tid];
        bool winner = true;
        for (int o2 = tid + 1; o2 < OO; ++o2)
            if (s_bdi[o2] == R) winner = false;
        if (winner) {
            // recompute kernel1's lab0 for row R (identical formula)
            float4 p = db[R];
            float px1 = p.x - p.z * 0.5f, py1 = p.y - p.w * 0.5f;
            float px2 = p.x + p.z * 0.5f, py2 = p.y + p.w * 0.5f;
            float area_b = (px2 - px1) * (py2 - py1);
            float best = -1.0f; int bi = 0;
            #pragma unroll
            for (int o = 0; o < OO; ++o) {
                float w = fmaxf(fminf(s_ax2[o], px2) - fmaxf(s_ax1[o], px1), 0.0f);
                float h = fmaxf(fminf(s_ay2[o], py2) - fmaxf(s_ay1[o], py1), 0.0f);
                float inter = w * h;
                float uni = s_area[o] + area_b - inter;
                float iou = inter * __builtin_amdgcn_rcpf(uni);
                if (iou > best) { best = iou; bi = o; }
            }
            int lab0 = (best < 0.5f) ? 0 : s_lab[bi];

            const float* x = cls + ((size_t)b * DD + R) * CC;
            float m = x[0];
            #pragma unroll
            for (int c = 1; c < CC; ++c) m = fmaxf(m, x[c]);
            float s = 0.0f;
            #pragma unroll
            for (int c = 0; c < CC; ++c) s += __expf(x[c] - m);
            float lse = m + __logf(s);
            float4 lp = loc_pred[(size_t)b * DD + R];

            if (lab0 > 0) {      // remove old positive contribution
                dce -= (lse - x[lab0]);
                dnp -= 1;
                float ax1 = s_ax1[bi], ay1 = s_ay1[bi], ax2 = s_ax2[bi], ay2 = s_ay2[bi];
                float cx = (ax1 + ax2) * 0.5f, cy = (ay1 + ay2) * 0.5f;
                float w = ax2 - ax1, h = ay2 - ay1;
                float gx = (cx - p.x) / (p.z / 10.0f);
                float gy = (cy - p.y) / (p.w / 10.0f);
                float gw = __logf(w / p.z) * 5.0f;
                float gh = __logf(h / p.w) * 5.0f;
                dsl1 -= smoothl1(lp.x - gx) + smoothl1(lp.y - gy)
                      + smoothl1(lp.z - gw) + smoothl1(lp.w - gh);
            } else {
                ce_neg[(size_t)b * DD + R] = 0.0f;   // row becomes positive
            }
            // add new contribution (box = tid, label = s_lab[tid] > 0)
            dce += (lse - x[s_lab[tid]]);
            dnp += 1;
            {
                float ax1 = s_ax1[tid], ay1 = s_ay1[tid], ax2 = s_ax2[tid], ay2 = s_ay2[tid];
                float cx = (ax1 + ax2) * 0.5f, cy = (ay1 + ay2) * 0.5f;
                float w = ax2 - ax1, h = ay2 - ay1;
                float gx = (cx - p.x) / (p.z / 10.0f);
                float gy = (cy - p.y) / (p.w / 10.0f);
                float gw = __logf(w / p.z) * 5.0f;
                float gh = __logf(h / p.w) * 5.0f;
                dsl1 += smoothl1(lp.x - gx) + smoothl1(lp.y - gy)
                      + smoothl1(lp.z - gw) + smoothl1(lp.w - gh);
            }
        }
    }
    if (tid < 64) {       // 16-lane butterfly (lanes 16-63 carry zeros)
        #pragma unroll
        for (int off = 8; off; off >>= 1) {
            dsl1 += __shfl_xor(dsl1, off, 16);
            dce  += __shfl_xor(dce, off, 16);
            dnp  += __shfl_xor(dnp, off, 16);
        }
        if (tid == 0) { s_dsl1 = dsl1; s_dce = dce; s_dnp = dnp; }
    }
    __syncthreads();      // drains ce_neg patch stores + LDS

    if (tid == 0) {
        float a = 0, c2 = 0; int n = 0;
        #pragma unroll
        for (int j = 0; j < NBLK_C; ++j) {
            a  += part_sl1[b * NBLK_C + j];
            c2 += part_ce[b * NBLK_C + j];
            n  += part_np[b * NBLK_C + j];
        }
        s_isl1 = a + s_dsl1; s_ice = c2 + s_dce; s_np = n + s_dnp;
    }
    __syncthreads();

    int k0 = 3 * s_np;
    if (k0 > DD) k0 = DD;

    float row = 0.0f;
    if (k0 > 0) {
        unsigned kx[NV];
        #pragma unroll
        for (int q = 0; q < NV; ++q) {
            int d = q * 256 + tid;
            float v = (d < DD) ? ce_neg[(size_t)b * DD + d] : 0.0f;
            unsigned u = __float_as_uint(v);
            kx[q] = u ^ ((unsigned)((int)u >> 31) | 0x80000000u);
        }
        unsigned prefix = 0u; int k = k0;
        #pragma unroll
        for (int p = 0; p < 4; ++p) {
            const int shift = 24 - 8 * p;
            hist[tid] = 0;
            __syncthreads();
            #pragma unroll
            for (int q = 0; q < NV; ++q) {
                if (p == 0 || ((kx[q] ^ prefix) >> (shift + 8)) == 0u)
                    atomicAdd(&hist[(kx[q] >> shift) & 255], 1);
            }
            __syncthreads();
            if (tid < 64) {
                int h0 = hist[255 - 4*tid], h1 = hist[254 - 4*tid],
                    h2 = hist[253 - 4*tid], h3 = hist[252 - 4*tid];
                int sl = h0 + h1 + h2 + h3;
                int run = sl;
                #pragma unroll
                for (int off = 1; off < 64; off <<= 1) {
                    int v = __shfl_up(run, off);
                    if (tid >= off) run += v;
                }
                int pre = run - sl;
                if (pre < k && k <= pre + sl) {
                    int hh[4] = {h0, h1, h2, h3};
                    int c = pre, byte = -1, knew = 0;
                    #pragma unroll
                    for (int j = 0; j < 4; ++j) {
                        if (byte < 0 && c + hh[j] >= k) { byte = 255 - 4*tid - j; knew = k - c; }
                        c += hh[j];
                    }
                    s_pk[0] = prefix | ((unsigned)byte << shift);
                    s_pk[1] = (unsigned)knew;
                }
            }
            __syncthreads();
            prefix = s_pk[0]; k = (int)s_pk[1];
        }
        unsigned vb = (prefix & 0x80000000u) ? (prefix ^ 0x80000000u) : ~prefix;
        float vk = __uint_as_float(vb);

        float ssum = 0.0f; int cgt = 0;
        #pragma unroll
        for (int q = 0; q < NV; ++q) {
            if (kx[q] > prefix) {
                unsigned u = (kx[q] & 0x80000000u) ? (kx[q] ^ 0x80000000u) : ~kx[q];
                ssum += __uint_as_float(u);
                ++cgt;
            }
        }
        #pragma unroll
        for (int off = 32; off; off >>= 1) { ssum += __shfl_xor(ssum, off); cgt += __shfl_xor(cgt, off); }
        if ((tid & 63) == 0) { s_f[tid >> 6] = ssum; s_c[tid >> 6] = cgt; }
        __syncthreads();
        row = s_f[0]+s_f[1]+s_f[2]+s_f[3]
            + (float)(k0 - (s_c[0]+s_c[1]+s_c[2]+s_c[3])) * vk;
    }

    if (tid == 0) {
        conf_neg_part[b] = row;
        img_sl1[b] = s_isl1; img_ce[b] = s_ice; img_np[b] = s_np;
        __threadfence();
        int prev = atomicAdd(done_counter, 1);
        s_last = (prev == BB - 1) ? 1 : 0;
    }
    __syncthreads();
    if (s_last) {
        __threadfence();
        float loc = 0.0f, cp = 0.0f, cn = 0.0f; int npt = 0;
        if (tid < BB) {
            loc = img_sl1[tid]; cp = img_ce[tid];
            cn = conf_neg_part[tid]; npt = img_np[tid];
        }
        #pragma unroll
        for (int off = 32; off; off >>= 1) {
            loc += __shfl_xor(loc, off);
            cp  += __shfl_xor(cp, off);
            cn  += __shfl_xor(cn, off);
            npt += __shfl_xor(npt, off);
        }
        const int w = tid >> 6;
        if ((tid & 63) == 0) { s_f[w*3+0] = loc; s_f[w*3+1] = cp; s_f[w*3+2] = cn; s_c[w] = npt; }
        __syncthreads();
        if (tid == 0) {
            float L = 0, P = 0, N = 0; int T = 0;
            #pragma unroll
            for (int q = 0; q < 4; ++q) { L += s_f[q*3]; P += s_f[q*3+1]; N += s_f[q*3+2]; T += s_c[q]; }
            float npf = (float)T;
            out[0] = L / (npf * 4.0f) + (N + P) / npf;
        }
    }
}

extern "C" void kernel_launch(void* const* d_in, const int* in_sizes, int n_in,
                              void* d_out, int out_size, void* d_ws, size_t ws_size,
                              hipStream_t stream) {
    (void)in_sizes; (void)n_in; (void)out_size; (void)ws_size;
    const float4* loc_pred  = (const float4*)d_in[0];
    const float*  cls_pred  = (const float*)d_in[1];
    const float4* gt_boxes  = (const float4*)d_in[2];
    const int*    gt_labels = (const int*)d_in[3];
    const float4* db        = (const float4*)d_in[4];

    char* ws = (char*)d_ws;
    size_t off = 0;
    auto alloc = [&](size_t bytes) { char* p = ws + off; off = (off + bytes + 15) & ~(size_t)15; return p; };

    unsigned long long* partial = (unsigned long long*)alloc((size_t)BB * OO * 8);
    int*   done_counter  = (int*)alloc(16);      // adjacent to partial -> one memset
    float* ce_neg        = (float*)alloc((size_t)BB * DD * 4);
    float* part_sl1      = (float*)alloc((size_t)NLB * 4);
    int*   part_np       = (int*)alloc((size_t)NLB * 4);
    float* part_ce       = (float*)alloc((size_t)NLB * 4);
    float* img_sl1       = (float*)alloc((size_t)BB * 4);
    float* img_ce        = (float*)alloc((size_t)BB * 4);
    int*   img_np        = (int*)alloc((size_t)BB * 4);
    float* conf_neg_part = (float*)alloc((size_t)BB * 4);

    // zero argmax targets + ticket counter (16 KB + 16 B, contiguous)
    hipMemsetAsync(partial, 0, (size_t)BB * OO * 8 + 16, stream);

    fused_all<<<dim3(NBLK_C, BB), 256, 0, stream>>>(loc_pred, cls_pred, gt_boxes,
                                                    gt_labels, db, partial,
                                                    ce_neg, part_sl1, part_np, part_ce);
    topk_final<<<BB, 256, 0, stream>>>(cls_pred, loc_pred, gt_boxes, gt_labels, db,
                                       partial, ce_neg, part_sl1, part_np, part_ce,
                                       img_sl1, img_ce, img_np, conf_neg_part,
                                       done_counter, (float*)d_out);
}